// Round 1
// 1752.453 us; speedup vs baseline: 1.0746x; 1.0746x over previous
//
#include <hip/hip_runtime.h>
#include <hip/hip_fp16.h>

#define B_ 256
#define T_ 1200
#define I_ 16
#define H_ 128

typedef __attribute__((ext_vector_type(2))) _Float16 h2;
typedef __attribute__((ext_vector_type(8))) _Float16 f16x8;

union f16x8u { f16x8 v; h2 h[4]; };

#if __has_builtin(__builtin_amdgcn_fdot2)
__device__ __forceinline__ float fdot2(h2 a, h2 b, float c) {
  return __builtin_amdgcn_fdot2(a, b, c, false);  // v_dot2_f32_f16
}
#else
__device__ __forceinline__ float fdot2(h2 a, h2 b, float c) {
  return fmaf((float)a.x, (float)b.x, fmaf((float)a.y, (float)b.y, c));
}
#endif

__device__ __forceinline__ float qsum(float x) {
  // sum across the 4 lanes of a quad via DPP quad_perm (VALU pipe)
  x += __int_as_float(__builtin_amdgcn_update_dpp(0, __float_as_int(x), 0xB1, 0xF, 0xF, true)); // xor 1
  x += __int_as_float(__builtin_amdgcn_update_dpp(0, __float_as_int(x), 0x4E, 0xF, 0xF, true)); // xor 2
  return x;
}

// Reduce quad-uniform values across the 16 quads of a wave.
// Input must be identical within each quad (true after qsum):
// then xor4 == xor7 (row_half_mirror) and xor8 == xor15 (row_mirror),
// so the first two levels run on the VALU DPP path instead of LDS shuffles.
__device__ __forceinline__ float wred(float x) {
  x += __int_as_float(__builtin_amdgcn_update_dpp(0, __float_as_int(x), 0x141, 0xF, 0xF, true)); // row_half_mirror ~ xor4
  x += __int_as_float(__builtin_amdgcn_update_dpp(0, __float_as_int(x), 0x140, 0xF, 0xF, true)); // row_mirror ~ xor8
  x += __shfl_xor(x, 16);
  x += __shfl_xor(x, 32);
  return x;
}

__device__ __forceinline__ float sigm(float x) {
  return __builtin_amdgcn_rcpf(1.f + __expf(-x));
}
__device__ __forceinline__ float tanh_(float x) {
  return 1.f - 2.f * __builtin_amdgcn_rcpf(1.f + __expf(2.f * x));
}

// Fully fused 2-layer LSTM + linear head. One WG (512 thr) per batch row.
// Quad owns h-index j (j = tid>>2); lane c = tid&3 holds k-slice [32c,32c+32)
// of W_hh0, W_ih1, W_hh1 rows {j, j+128, j+256, j+384} as fp16x2 in VGPRs
// (3 * 64 = 192 VGPRs). h state in tiny LDS double buffers (fp16).
//
// amdgpu_waves_per_eu(2,2): grid is 256 blocks on 256 CUs -> exactly 1 block
// (8 waves = 2 waves/SIMD) per CU, so pin the allocator to that occupancy and
// give it the full 256-VGPR budget. Without the max bound the allocator capped
// at 128 VGPRs chasing unreachable occupancy and spilled ~180 regs/thread
// (rocprof: VGPR_Count=128, WRITE_SIZE=95 MB vs 1.2 MB ideal).
__global__ __attribute__((amdgpu_waves_per_eu(2, 2)))
__launch_bounds__(512) void lstm_fused(
    const float* __restrict__ xin,
    const float* __restrict__ Wih0, const float* __restrict__ Whh0,
    const float* __restrict__ bih0, const float* __restrict__ bhh0,
    const float* __restrict__ Wih1, const float* __restrict__ Whh1,
    const float* __restrict__ bih1, const float* __restrict__ bhh1,
    const float* __restrict__ Wlin, const float* __restrict__ blin,
    float* __restrict__ out)
{
  __shared__ __align__(16) __half buf0[2][H_];   // layer-0 h, double buffered
  __shared__ __align__(16) __half buf1[2][H_];   // layer-1 h
  __shared__ __align__(16) float red[2][8];      // out-reduction per wave

  const int tid = threadIdx.x;
  const int c = tid & 3;
  const int j = tid >> 2;
  const int b = blockIdx.x;
  const int wv = tid >> 6;

  h2 w0[4][16], wi[4][16], wh[4][16];  // fp16x2 weight slices
  h2 wx[4][2];                         // W_ih0 slice (K=16)
  float bs0[4], bs1[4];

#pragma unroll
  for (int q = 0; q < 4; ++q) {
    const int g = q * H_ + j;
    const float* p0 = Whh0 + (size_t)g * H_ + c * 32;
    const float* p1 = Wih1 + (size_t)g * H_ + c * 32;
    const float* p2 = Whh1 + (size_t)g * H_ + c * 32;
#pragma unroll
    for (int i = 0; i < 8; ++i) {
      float4 v = *(const float4*)(p0 + 4 * i);
      w0[q][2*i].x   = (_Float16)v.x; w0[q][2*i].y   = (_Float16)v.y;
      w0[q][2*i+1].x = (_Float16)v.z; w0[q][2*i+1].y = (_Float16)v.w;
      v = *(const float4*)(p1 + 4 * i);
      wi[q][2*i].x   = (_Float16)v.x; wi[q][2*i].y   = (_Float16)v.y;
      wi[q][2*i+1].x = (_Float16)v.z; wi[q][2*i+1].y = (_Float16)v.w;
      v = *(const float4*)(p2 + 4 * i);
      wh[q][2*i].x   = (_Float16)v.x; wh[q][2*i].y   = (_Float16)v.y;
      wh[q][2*i+1].x = (_Float16)v.z; wh[q][2*i+1].y = (_Float16)v.w;
    }
    const float4 vx = *(const float4*)(Wih0 + (size_t)g * I_ + 4 * c);
    wx[q][0].x = (_Float16)vx.x; wx[q][0].y = (_Float16)vx.y;
    wx[q][1].x = (_Float16)vx.z; wx[q][1].y = (_Float16)vx.w;
    bs0[q] = bih0[g] + bhh0[g];
    bs1[q] = bih1[g] + bhh1[g];
  }
  const float wl = Wlin[j];            // head weight (4x redundant per quad,
                                       // but wred only sums across quads)
  const float bl = blin[0];

  if (tid < H_) {
    buf0[0][tid] = __float2half(0.f);
    buf1[0][tid] = __float2half(0.f);
  }
  float cst0 = 0.f, cst1 = 0.f;
  const float* xp = xin + (size_t)b * T_ * I_ + 4 * c;
  float* op = out + (size_t)b * T_;
  __syncthreads();

#pragma unroll 2
  for (int t = 0; t < T_; ++t) {
    const int rb = t & 1;
    // ---------------- layer 0 ----------------
    const float4 xv = *(const float4*)xp; xp += I_;  // issue early
    float a0 = 0.f, a1 = 0.f, a2 = 0.f, a3 = 0.f;
#pragma unroll
    for (int i = 0; i < 4; ++i) {
      f16x8u u; u.v = *(const f16x8*)(&buf0[rb][c * 32 + i * 8]);  // broadcast read
#pragma unroll
      for (int p = 0; p < 4; ++p) {
        const h2 hv = u.h[p];
        a0 = fdot2(w0[0][4 * i + p], hv, a0);
        a1 = fdot2(w0[1][4 * i + p], hv, a1);
        a2 = fdot2(w0[2][4 * i + p], hv, a2);
        a3 = fdot2(w0[3][4 * i + p], hv, a3);
      }
    }
    h2 xa, xb;
    xa.x = (_Float16)xv.x; xa.y = (_Float16)xv.y;
    xb.x = (_Float16)xv.z; xb.y = (_Float16)xv.w;
    a0 = fdot2(wx[0][0], xa, fdot2(wx[0][1], xb, a0));
    a1 = fdot2(wx[1][0], xa, fdot2(wx[1][1], xb, a1));
    a2 = fdot2(wx[2][0], xa, fdot2(wx[2][1], xb, a2));
    a3 = fdot2(wx[3][0], xa, fdot2(wx[3][1], xb, a3));
    {
      const float g0 = qsum(a0) + bs0[0];
      const float g1 = qsum(a1) + bs0[1];
      const float g2 = qsum(a2) + bs0[2];
      const float g3 = qsum(a3) + bs0[3];
      const float ig = sigm(g0), fg = sigm(g1), gg = tanh_(g2), og = sigm(g3);
      cst0 = fg * cst0 + ig * gg;
      const float h0v = og * tanh_(cst0);
      if (c == 0) buf0[rb ^ 1][j] = __float2half(h0v);
    }
    __syncthreads();
    // ---------------- layer 1 ----------------
    a0 = 0.f; a1 = 0.f; a2 = 0.f; a3 = 0.f;
#pragma unroll
    for (int i = 0; i < 4; ++i) {
      f16x8u u; u.v = *(const f16x8*)(&buf0[rb ^ 1][c * 32 + i * 8]);  // h0_t
#pragma unroll
      for (int p = 0; p < 4; ++p) {
        const h2 hv = u.h[p];
        a0 = fdot2(wi[0][4 * i + p], hv, a0);
        a1 = fdot2(wi[1][4 * i + p], hv, a1);
        a2 = fdot2(wi[2][4 * i + p], hv, a2);
        a3 = fdot2(wi[3][4 * i + p], hv, a3);
      }
    }
#pragma unroll
    for (int i = 0; i < 4; ++i) {
      f16x8u u; u.v = *(const f16x8*)(&buf1[rb][c * 32 + i * 8]);  // h1_{t-1}
#pragma unroll
      for (int p = 0; p < 4; ++p) {
        const h2 hv = u.h[p];
        a0 = fdot2(wh[0][4 * i + p], hv, a0);
        a1 = fdot2(wh[1][4 * i + p], hv, a1);
        a2 = fdot2(wh[2][4 * i + p], hv, a2);
        a3 = fdot2(wh[3][4 * i + p], hv, a3);
      }
    }
    const float g0 = qsum(a0) + bs1[0];
    const float g1 = qsum(a1) + bs1[1];
    const float g2 = qsum(a2) + bs1[2];
    const float g3 = qsum(a3) + bs1[3];
    const float ig = sigm(g0), fg = sigm(g1), gg = tanh_(g2), og = sigm(g3);
    cst1 = fg * cst1 + ig * gg;
    const float h1v = og * tanh_(cst1);
    if (c == 0) buf1[rb ^ 1][j] = __float2half(h1v);
    // fused relu + W_lin dot: h1v/wl are quad-uniform; wred sums the 16
    // quads of each wave (4 DPP/shfl levels instead of 6).
    float val = wred(fmaxf(h1v, 0.f) * wl);
    if ((tid & 63) == 0) red[rb][wv] = val;
    __syncthreads();
    // rotate the final 8-value sum across waves to avoid a fixed straggler.
    // Safe: next write to red[rb] is at t+2, which is >=2 barriers away.
    if (tid == ((t & 7) << 6)) {
      const float4 r0 = *(const float4*)(&red[rb][0]);
      const float4 r1 = *(const float4*)(&red[rb][4]);
      op[t] = bl + r0.x + r0.y + r0.z + r0.w + r1.x + r1.y + r1.z + r1.w;
    }
  }
}

extern "C" void kernel_launch(void* const* d_in, const int* in_sizes, int n_in,
                              void* d_out, int out_size, void* d_ws, size_t ws_size,
                              hipStream_t stream) {
  // Zero-workspace design: d_ws deliberately unused.
  lstm_fused<<<B_, 512, 0, stream>>>(
      (const float*)d_in[0],
      (const float*)d_in[1], (const float*)d_in[2],
      (const float*)d_in[3], (const float*)d_in[4],
      (const float*)d_in[5], (const float*)d_in[6],
      (const float*)d_in[7], (const float*)d_in[8],
      (const float*)d_in[9], (const float*)d_in[10],
      (float*)d_out);
}